// Round 13
// baseline (251.707 us; speedup 1.0000x reference)
//
#include <hip/hip_runtime.h>
#include <hip/hip_bf16.h>

typedef unsigned short u16;
typedef __bf16 bf16x8 __attribute__((ext_vector_type(8)));
typedef float floatx4 __attribute__((ext_vector_type(4)));

#define B_ 4
#define N_ 2048
#define C_ 1024
#define H_ 16
#define HD_ 64

__device__ __forceinline__ float b2f(u16 u) {
    union { float f; unsigned int i; } v; v.i = ((unsigned int)u) << 16; return v.f;
}
__device__ __forceinline__ u16 f2b(float f) {
    union { float f; unsigned int i; } v; v.f = f;
    unsigned int i = v.i;
    unsigned int r = i + 0x7FFFu + ((i >> 16) & 1u);
    return (u16)(r >> 16);
}
__device__ __forceinline__ unsigned int pk2(float a, float b) {
    __hip_bfloat162 t = __float22bfloat162_rn(float2{a, b});
    unsigned int u; __builtin_memcpy(&u, &t, 4); return u;
}
// hardware exp2 via BUILTIN (not inline asm): lowers to v_exp_f32 AND lets
// the backend insert the gfx950 trans-use wait state (R12 lesson: inline-asm
// producer hides the opcode from the hazard recognizer -> garbage).
__device__ __forceinline__ float fexp2(float x) {
    return __builtin_amdgcn_exp2f(x);
}
// packed f32->bf16 RNE, 1 VOP3 instr (T12 recipe, m214v22-proven).  Safe in
// inline asm: cvt_pk is NOT a trans op (no producer hazard), and consumer-
// side hazard checks see asm register uses normally.
__device__ __forceinline__ unsigned int pkraw(float a, float b) {
    unsigned int u;
    asm("v_cvt_pk_bf16_f32 %0, %1, %2" : "=v"(u) : "v"(a), "v"(b));
    return u;
}
// async global->LDS, 16B per lane; LDS dest = wave-uniform base + lane*16
__device__ __forceinline__ void async16(const u16* g, u16* l) {
    __builtin_amdgcn_global_load_lds((const __attribute__((address_space(1))) unsigned int*)g,
                                     (__attribute__((address_space(3))) unsigned int*)l,
                                     16, 0, 0);
}
__device__ __forceinline__ void async16p(const void* g, void* l) {
    __builtin_amdgcn_global_load_lds((const __attribute__((address_space(1))) unsigned int*)g,
                                     (__attribute__((address_space(3))) unsigned int*)l,
                                     16, 0, 0);
}

// ---------------------------------------------------------------------------
// Kernel 1: x = inputs(fp32) + sinusoidal PE  ->  bf16 x.
// ---------------------------------------------------------------------------
__global__ __launch_bounds__(256) void pe_add_kernel(const float* __restrict__ in,
                                                     u16* __restrict__ x) {
    int idx = blockIdx.x * 256 + threadIdx.x;      // pair index, total B*N*C/2
    int cp  = idx & 511;                            // C/2 = 512 pairs per row
    int row = idx >> 9;                             // b*N + n
    int n   = row & (N_ - 1);
    float r = exp2f(-13.287712379549449f * ((float)cp * (1.0f / 512.0f)));
    float ang = (float)n * r;
    float s, c;
    sincosf(ang, &s, &c);
    float2 pr = ((const float2*)in)[idx];
    unsigned int o = ((unsigned int)f2b(pr.y + c) << 16) | (unsigned int)f2b(pr.x + s);
    ((unsigned int*)x)[idx] = o;
}

// ---------------------------------------------------------------------------
// Kernel 2: transpose W_qkv fp32 [1024][3072] -> bf16 Wt [3072][1024].
// ---------------------------------------------------------------------------
__global__ __launch_bounds__(256) void wt_kernel(const float* __restrict__ W,
                                                 u16* __restrict__ Wt) {
    __shared__ u16 tile[32][33];
    int bx = blockIdx.x;            // over 3072/32 = 96
    int by = blockIdx.y;            // over 1024/32 = 32
    int tx = threadIdx.x & 31;
    int ty = threadIdx.x >> 5;      // 0..7
    for (int i = 0; i < 32; i += 8)
        tile[ty + i][tx] = f2b(W[(size_t)(by * 32 + ty + i) * 3072 + bx * 32 + tx]);
    __syncthreads();
    for (int i = 0; i < 32; i += 8)
        Wt[(size_t)(bx * 32 + ty + i) * 1024 + by * 32 + tx] = tile[tx][ty + i];
}

// ---------------------------------------------------------------------------
// Kernel 3: QKV GEMM, BK=64 — R14: + bijective XCD swizzle (1536 % 8 == 0).
// Blocks on one XCD cover a contiguous n-panel-major range: XCD x gets
// lin in [x*192, x*192+192) = 3 B-panels (768 KB, L2-resident) x 64 m-blocks.
// A panels stream through L3 (X = 16 MB fits Infinity Cache).
// ---------------------------------------------------------------------------
__global__ __launch_bounds__(256) void qkv_gemm_kernel(const u16* __restrict__ X,
                                                       const u16* __restrict__ Wt,
                                                       u16* __restrict__ q,
                                                       u16* __restrict__ k,
                                                       u16* __restrict__ vt) {
    __shared__ u16 As[128 * 64];
    __shared__ u16 Bs[128 * 64];
    int tid  = threadIdx.x;
    int wave = tid >> 6, lane = tid & 63, l15 = lane & 15, quad = lane >> 4;
    int bid = blockIdx.x;
    int lin = (bid & 7) * 192 + (bid >> 3);        // bijective: 1536 = 8*192
    int m0 = (lin & 63) * 128;                     // 64 m-blocks fastest
    int n0 = (lin >> 6) * 128;                     // 24 n-blocks
    int wm = (wave & 1) * 64;
    int wn = (wave >> 1) * 64;

    floatx4 acc[4][4];
    for (int i = 0; i < 4; i++)
        for (int j = 0; j < 4; j++)
            acc[i][j] = floatx4{0.f, 0.f, 0.f, 0.f};

    // staging: wave stages rows [wave*32, wave*32+32), 4 instrs of 8 rows each.
    // LDS[r][c'] = global[r][c' ^ (r&7)]  (c' = lane&7, r&7 = lane>>3)
    int rowOff = wave * 32 + (lane >> 3);
    int colSw  = ((lane & 7) ^ (lane >> 3)) * 8;
    const u16* gA = X  + (size_t)(m0 + rowOff) * 1024 + colSw;
    const u16* gB = Wt + (size_t)(n0 + rowOff) * 1024 + colSw;
    u16* lA = As + wave * 2048;                    // 32 rows * 64 elems
    u16* lB = Bs + wave * 2048;

    // loop-invariant frag read offsets: chunk g=kh*4+quad stored at g^(l15&7)
    int swl = l15 & 7;
    int aB0 = (wm + l15) * 64 + ((quad ^ swl) * 8);
    int aB1 = (wm + l15) * 64 + (((4 + quad) ^ swl) * 8);
    int bB0 = (wn + l15) * 64 + ((quad ^ swl) * 8);
    int bB1 = (wn + l15) * 64 + (((4 + quad) ^ swl) * 8);

    for (int k0 = 0; k0 < 1024; k0 += 64) {
        __syncthreads();                            // prev tile consumed
        async16(gA + k0,             lA);
        async16(gA + k0 +  8 * 1024, lA + 512);
        async16(gA + k0 + 16 * 1024, lA + 1024);
        async16(gA + k0 + 24 * 1024, lA + 1536);
        async16(gB + k0,             lB);
        async16(gB + k0 +  8 * 1024, lB + 512);
        async16(gB + k0 + 16 * 1024, lB + 1024);
        async16(gB + k0 + 24 * 1024, lB + 1536);
        __syncthreads();                            // vmcnt(0) drain + barrier

        bf16x8 af[4][2], bf[4][2];
        for (int i = 0; i < 4; i++) {
            af[i][0] = *(const bf16x8*)(As + aB0 + i * 16 * 64);
            af[i][1] = *(const bf16x8*)(As + aB1 + i * 16 * 64);
        }
        for (int j = 0; j < 4; j++) {
            bf[j][0] = *(const bf16x8*)(Bs + bB0 + j * 16 * 64);
            bf[j][1] = *(const bf16x8*)(Bs + bB1 + j * 16 * 64);
        }
        for (int i = 0; i < 4; i++)
            for (int j = 0; j < 4; j++) {
                acc[i][j] = __builtin_amdgcn_mfma_f32_16x16x32_bf16(af[i][0], bf[j][0], acc[i][j], 0, 0, 0);
                acc[i][j] = __builtin_amdgcn_mfma_f32_16x16x32_bf16(af[i][1], bf[j][1], acc[i][j], 0, 0, 0);
            }
    }

    // epilogue: C[m][n], m = m0+wm+i*16+quad*4+r, n_col = n0+wn+j*16+l15
    const float QSC = 0.125f * 1.44269504f;        // folded scale*log2e for q
    for (int i = 0; i < 4; i++) {
        int gm   = m0 + wm + i * 16 + quad * 4;
        int b    = gm >> 11;                       // / 2048
        int nloc = gm & 2047;
        for (int j = 0; j < 4; j++) {
            int gn    = n0 + wn + j * 16 + l15;
            int which = gn >> 10;                  // 0=q 1=k 2=v (wave-uniform)
            int cc    = gn & 1023;
            int h     = cc >> 6;
            int d     = cc & 63;
            size_t bh = (size_t)(b * 16 + h);
            if (which == 2) {
                ushort4 w4;
                w4.x = f2b(acc[i][j][0]);
                w4.y = f2b(acc[i][j][1]);
                w4.z = f2b(acc[i][j][2]);
                w4.w = f2b(acc[i][j][3]);
                *(ushort4*)(vt + (bh * 64 + d) * 2048 + nloc) = w4;  // 4 consecutive n
            } else {
                u16* dst = (which == 0) ? q : k;
                float sc = (which == 0) ? QSC : 1.0f;
                for (int r = 0; r < 4; r++)
                    dst[(bh * 2048 + nloc + r) * 64 + d] = f2b(acc[i][j][r] * sc);
            }
        }
    }
}

// ---------------------------------------------------------------------------
// Kernel 4: flash attention — R14: R13 + cvt_pk bf16 pack (isolated re-add).
// R13 passed (absmax 0.0078, 105 us, VALU 42 / Mfma 32).  R12's corruption
// is attributed to the exp trans-hazard (producer-opcode invisible in asm);
// cvt_pk is plain VOP3 -> safe.  Only change vs R13: pk2 -> pkraw.
// Falsifiers: absmax fails -> cvt_pk implicated after all, revert; dur flat
// with VALU down -> VALU not binding -> GEMM 8-phase rewrite next.
// ---------------------------------------------------------------------------
__global__ __launch_bounds__(256, 4) void attn_kernel(const u16* __restrict__ q,
                                                      const u16* __restrict__ k,
                                                      const u16* __restrict__ vt,
                                                      const float* __restrict__ mask,
                                                      float* __restrict__ out) {
    __shared__ u16 Ks[3][32 * 64];    // [key][d]  linear, source-swizzled (12 KB)
    __shared__ u16 Vs[3][64 * 32];    // [d][key]  linear, source-swizzled (12 KB)
    __shared__ u16 Ps[4][32 * 40];    // per-wave [q][key], stride 40 (10 KB)
    __shared__ __align__(16) float Msr[3][256];    // mask tile ring (3 KB; 32 real + pad)

    int tid  = threadIdx.x;
    int wave = tid >> 6, lane = tid & 63, l15 = lane & 15, quad = lane >> 4;
    int bid = blockIdx.x;             // 1D: bh fastest -> XCD = bh%8 cluster
    int bh = bid & 63, qb = bid >> 6;
    int b = bh >> 4, h = bh & 15;
    size_t base = (size_t)bh * (N_ * 64);
    int q0 = qb * 128 + wave * 32;
    const float* mkb = mask + b * N_;

    // Q as B-operand fragments (q pre-scaled by 0.125*log2e at GEMM time)
    bf16x8 qf[2][2];
#pragma unroll
    for (int s = 0; s < 2; s++)
#pragma unroll
        for (int dc = 0; dc < 2; dc++)
            qf[s][dc] = *(const bf16x8*)(q + base + (size_t)(q0 + s * 16 + l15) * 64 + dc * 32 + quad * 8);

    const float L2E = 1.44269504f;
    float nmq[2];
    nmq[0] = -L2E * mkb[q0 + l15];
    nmq[1] = -L2E * mkb[q0 + 16 + l15];

    // all-ones B-fragment for the denominator MFMA
    bf16x8 onef;
#pragma unroll
    for (int i = 0; i < 8; i++) onef[i] = (__bf16)1.0f;

    floatx4 acc[2][4];                // [s][dt] PV accumulator
    floatx4 accl[2];                  // [s]     row-sum accumulator (denominator)
#pragma unroll
    for (int s = 0; s < 2; s++) {
        accl[s] = floatx4{0.f, 0.f, 0.f, 0.f};
#pragma unroll
        for (int dt = 0; dt < 4; dt++)
            acc[s][dt] = floatx4{0.f, 0.f, 0.f, 0.f};
    }

    // async16 staging, 1 K + 1 V + 1 M instr per wave per tile:
    //   K: 8 rows x 8 chunks;  wave w covers K rows [w*8,  w*8+8)
    //   V: 16 rows x 4 chunks; wave w covers V rows [w*16, w*16+16)
    //   M: 128 B mask tile, all waves duplicate (lane&7 source clamp)
    int krow = wave * 8  + (lane >> 3);
    int kcol = ((lane & 7) ^ (lane >> 3)) * 8;            // chunk ^ (r&7)
    int vrow = wave * 16 + (lane >> 2);
    int vcol = ((lane & 3) ^ ((lane >> 2) & 3)) * 8;      // chunk ^ (r&3)
    const u16* gK = k  + base + (size_t)krow * 64 + kcol;            // += kt*64
    const u16* gV = vt + ((size_t)bh * 64 + vrow) * 2048 + vcol;     // += kt
    const float* gM = mkb + (lane & 7) * 4;                          // += kt
    int wof = wave * 512;             // wave-uniform LDS stage offset

    // loop-invariant swizzled frag-read offsets
    int a0 = ((quad    ) ^ (l15 & 7)) * 8;    // K chunks 0..7  -> d = quad*8
    int a1 = ((4 + quad) ^ (l15 & 7)) * 8;    //                -> d = 32+quad*8
    int av = ( quad      ^ (l15 & 3)) * 8;    // V chunks 0..3  -> key = quad*8

    u16* Pw = Ps[wave];

    // one KVBLK=32 tile body; barrier + counted vmcnt(3) at TOP.
    auto TILE = [&](int kt, const u16* Kb, const u16* Vb, const float* Mb,
                    u16* Kn, u16* Vn, float* Mn) {
        asm volatile("s_waitcnt vmcnt(3)" ::: "memory");
        __builtin_amdgcn_s_barrier();
        __builtin_amdgcn_sched_barrier(0);
        int nkt = kt + 64; if (nkt > N_ - 32) nkt = N_ - 32;   // clamp (dead restage)
        async16(gK + (size_t)nkt * 64, Kn);
        async16(gV + nkt,              Vn);
        async16p(gM + nkt,             Mn);
        float4 mkv0 = *(const float4*)(Mb + quad * 4);
        float4 mkv1 = *(const float4*)(Mb + 16 + quad * 4);
        // S^T (key x q): C seeded with nmq*mk (mask add for free); p = exp2(S)
#pragma unroll
        for (int t = 0; t < 2; t++) {
            bf16x8 kf0 = *(const bf16x8*)(Kb + (t * 16 + l15) * 64 + a0);
            bf16x8 kf1 = *(const bf16x8*)(Kb + (t * 16 + l15) * 64 + a1);
            float4 mk = t ? mkv1 : mkv0;
#pragma unroll
            for (int s = 0; s < 2; s++) {
                floatx4 sa;
                sa[0] = nmq[s] * mk.x;
                sa[1] = nmq[s] * mk.y;
                sa[2] = nmq[s] * mk.z;
                sa[3] = nmq[s] * mk.w;
                __builtin_amdgcn_s_setprio(1);
                sa = __builtin_amdgcn_mfma_f32_16x16x32_bf16(kf0, qf[s][0], sa, 0, 0, 0);
                sa = __builtin_amdgcn_mfma_f32_16x16x32_bf16(kf1, qf[s][1], sa, 0, 0, 0);
                __builtin_amdgcn_s_setprio(0);
                float p0 = fexp2(sa[0]);
                float p1 = fexp2(sa[1]);
                float p2 = fexp2(sa[2]);
                float p3 = fexp2(sa[3]);
                uint2 w; w.x = pkraw(p0, p1); w.y = pkraw(p2, p3);
                *(uint2*)(Pw + (s * 16 + l15) * 40 + t * 16 + quad * 4) = w;
            }
        }
        // PV (+ denominator via ones-MFMA): K-dim = 32 keys = 1 MFMA each
        bf16x8 pf0 = *(const bf16x8*)(Pw + l15 * 40 + quad * 8);
        bf16x8 pf1 = *(const bf16x8*)(Pw + (16 + l15) * 40 + quad * 8);
        __builtin_amdgcn_s_setprio(1);
        accl[0] = __builtin_amdgcn_mfma_f32_16x16x32_bf16(pf0, onef, accl[0], 0, 0, 0);
        accl[1] = __builtin_amdgcn_mfma_f32_16x16x32_bf16(pf1, onef, accl[1], 0, 0, 0);
        __builtin_amdgcn_s_setprio(0);
#pragma unroll
        for (int dt = 0; dt < 4; dt++) {
            bf16x8 vf = *(const bf16x8*)(Vb + (dt * 16 + l15) * 32 + av);
            __builtin_amdgcn_s_setprio(1);
            acc[0][dt] = __builtin_amdgcn_mfma_f32_16x16x32_bf16(pf0, vf, acc[0][dt], 0, 0, 0);
            acc[1][dt] = __builtin_amdgcn_mfma_f32_16x16x32_bf16(pf1, vf, acc[1][dt], 0, 0, 0);
            __builtin_amdgcn_s_setprio(0);
        }
    };

    // prologue: drain qf/nmq loads so the vmcnt FIFO is clean, then stage
    // tiles 0,1 (3 ops each) and full-drain once.
    asm volatile("s_waitcnt vmcnt(0)" ::: "memory");
    async16(gK,            Ks[0] + wof);
    async16(gV,            Vs[0] + wof);
    async16p(gM,           Msr[0]);
    async16(gK + 32 * 64,  Ks[1] + wof);
    async16(gV + 32,       Vs[1] + wof);
    async16p(gM + 32,      Msr[1]);
    __syncthreads();

    // 64 tiles: 21 x 3 (ring-3, static buffers) + 1 tail
    for (int m = 0; m < 21; ++m) {
        int kt = m * 96;
        TILE(kt,      Ks[0], Vs[0], Msr[0], Ks[2] + wof, Vs[2] + wof, Msr[2]);
        TILE(kt + 32, Ks[1], Vs[1], Msr[1], Ks[0] + wof, Vs[0] + wof, Msr[0]);
        TILE(kt + 64, Ks[2], Vs[2], Msr[2], Ks[1] + wof, Vs[1] + wof, Msr[1]);
    }
    TILE(2016, Ks[0], Vs[0], Msr[0], Ks[2] + wof, Vs[2] + wof, Msr[2]);  // tile 63

    // epilogue: accl[s][r] = l(q = s*16+quad*4+r) — per-lane, no shuffles.
    // acc C-layout: col=l15=d, row=quad*4+r=q (same row-map as accl).
#pragma unroll
    for (int s = 0; s < 2; s++) {
#pragma unroll
        for (int r = 0; r < 4; r++) {
            float ir = 1.0f / accl[s][r];
            int qrow = q0 + s * 16 + quad * 4 + r;
            float* orow = out + ((size_t)(b * N_ + qrow)) * C_ + h * 64;
#pragma unroll
            for (int dt = 0; dt < 4; dt++)
                orow[dt * 16 + l15] = acc[s][dt][r] * ir;
        }
    }
}

// ---------------------------------------------------------------------------
extern "C" void kernel_launch(void* const* d_in, const int* in_sizes, int n_in,
                              void* d_out, int out_size, void* d_ws, size_t ws_size,
                              hipStream_t stream) {
    const float* inp  = (const float*)d_in[0];   // inputs  [B,N,C] fp32
    const float* mask = (const float*)d_in[1];   // mask    [B,N]   fp32
    const float* W    = (const float*)d_in[2];   // W_qkv   [C,3C]  fp32
    float* out = (float*)d_out;                  // [B,N,C] fp32

    char* ws = (char*)d_ws;
    u16* x  = (u16*)ws;                              // 16 MB  x=in+PE bf16
    u16* Wt = (u16*)(ws + 16777216);                 // 6 MB   W^T bf16
    u16* q  = (u16*)(ws + 23068672);                 // [B,H,N,64] bf16 (pre-scaled)
    u16* k  = q + 8388608;
    u16* vt = k + 8388608;                           // [B,H,64,N] bf16 (v transposed)

    pe_add_kernel<<<16384, 256, 0, stream>>>(inp, x);
    wt_kernel<<<dim3(96, 32), 256, 0, stream>>>(W, Wt);
    qkv_gemm_kernel<<<1536, 256, 0, stream>>>(x, Wt, q, k, vt);
    attn_kernel<<<1024, 256, 0, stream>>>(q, k, vt, mask, out);
}

// Round 14
// 232.184 us; speedup vs baseline: 1.0841x; 1.0841x over previous
//
#include <hip/hip_runtime.h>
#include <hip/hip_bf16.h>

typedef unsigned short u16;
typedef __bf16 bf16x8 __attribute__((ext_vector_type(8)));
typedef float floatx4 __attribute__((ext_vector_type(4)));

#define B_ 4
#define N_ 2048
#define C_ 1024
#define H_ 16
#define HD_ 64

__device__ __forceinline__ float b2f(u16 u) {
    union { float f; unsigned int i; } v; v.i = ((unsigned int)u) << 16; return v.f;
}
__device__ __forceinline__ u16 f2b(float f) {
    union { float f; unsigned int i; } v; v.f = f;
    unsigned int i = v.i;
    unsigned int r = i + 0x7FFFu + ((i >> 16) & 1u);
    return (u16)(r >> 16);
}
// hardware exp2 via BUILTIN (not inline asm): lowers to v_exp_f32 AND lets
// the backend insert the gfx950 trans-use wait state (R12 lesson: inline-asm
// producer hides the opcode from the hazard recognizer -> garbage).
__device__ __forceinline__ float fexp2(float x) {
    return __builtin_amdgcn_exp2f(x);
}
// packed f32->bf16 RNE, 1 VOP3 instr (R14-proven safe: not a trans op).
__device__ __forceinline__ unsigned int pkraw(float a, float b) {
    unsigned int u;
    asm("v_cvt_pk_bf16_f32 %0, %1, %2" : "=v"(u) : "v"(a), "v"(b));
    return u;
}
// async global->LDS, 16B per lane; LDS dest = wave-uniform base + lane*16
__device__ __forceinline__ void async16(const u16* g, u16* l) {
    __builtin_amdgcn_global_load_lds((const __attribute__((address_space(1))) unsigned int*)g,
                                     (__attribute__((address_space(3))) unsigned int*)l,
                                     16, 0, 0);
}
__device__ __forceinline__ void async16p(const void* g, void* l) {
    __builtin_amdgcn_global_load_lds((const __attribute__((address_space(1))) unsigned int*)g,
                                     (__attribute__((address_space(3))) unsigned int*)l,
                                     16, 0, 0);
}

// ---------------------------------------------------------------------------
// Kernel 1: x = inputs(fp32) + sinusoidal PE  ->  bf16 x.
// ---------------------------------------------------------------------------
__global__ __launch_bounds__(256) void pe_add_kernel(const float* __restrict__ in,
                                                     u16* __restrict__ x) {
    int idx = blockIdx.x * 256 + threadIdx.x;      // pair index, total B*N*C/2
    int cp  = idx & 511;                            // C/2 = 512 pairs per row
    int row = idx >> 9;                             // b*N + n
    int n   = row & (N_ - 1);
    float r = exp2f(-13.287712379549449f * ((float)cp * (1.0f / 512.0f)));
    float ang = (float)n * r;
    float s, c;
    sincosf(ang, &s, &c);
    float2 pr = ((const float2*)in)[idx];
    unsigned int o = ((unsigned int)f2b(pr.y + c) << 16) | (unsigned int)f2b(pr.x + s);
    ((unsigned int*)x)[idx] = o;
}

// ---------------------------------------------------------------------------
// Kernel 2: transpose W_qkv fp32 [1024][3072] -> bf16 Wt [3072][1024].
// ---------------------------------------------------------------------------
__global__ __launch_bounds__(256) void wt_kernel(const float* __restrict__ W,
                                                 u16* __restrict__ Wt) {
    __shared__ u16 tile[32][33];
    int bx = blockIdx.x;            // over 3072/32 = 96
    int by = blockIdx.y;            // over 1024/32 = 32
    int tx = threadIdx.x & 31;
    int ty = threadIdx.x >> 5;      // 0..7
    for (int i = 0; i < 32; i += 8)
        tile[ty + i][tx] = f2b(W[(size_t)(by * 32 + ty + i) * 3072 + bx * 32 + tx]);
    __syncthreads();
    for (int i = 0; i < 32; i += 8)
        Wt[(size_t)(bx * 32 + ty + i) * 1024 + by * 32 + tx] = tile[tx][ty + i];
}

// ---------------------------------------------------------------------------
// Kernel 3: QKV GEMM, BK=64 — R15: REVERTED to R13 grid (dim3(64,24)).
// R14's "XCD swizzle" cost ~15 us: the old grid already gives each XCD 8
// L2-resident A-panels (linear%8 = m%8) with B shared in lockstep via L3;
// the swizzle replaced that with full-A streaming per XCD.
// ---------------------------------------------------------------------------
__global__ __launch_bounds__(256) void qkv_gemm_kernel(const u16* __restrict__ X,
                                                       const u16* __restrict__ Wt,
                                                       u16* __restrict__ q,
                                                       u16* __restrict__ k,
                                                       u16* __restrict__ vt) {
    __shared__ u16 As[128 * 64];
    __shared__ u16 Bs[128 * 64];
    int tid  = threadIdx.x;
    int wave = tid >> 6, lane = tid & 63, l15 = lane & 15, quad = lane >> 4;
    int m0 = blockIdx.x * 128;
    int n0 = blockIdx.y * 128;
    int wm = (wave & 1) * 64;
    int wn = (wave >> 1) * 64;

    floatx4 acc[4][4];
    for (int i = 0; i < 4; i++)
        for (int j = 0; j < 4; j++)
            acc[i][j] = floatx4{0.f, 0.f, 0.f, 0.f};

    // staging: wave stages rows [wave*32, wave*32+32), 4 instrs of 8 rows each.
    // LDS[r][c'] = global[r][c' ^ (r&7)]  (c' = lane&7, r&7 = lane>>3)
    int rowOff = wave * 32 + (lane >> 3);
    int colSw  = ((lane & 7) ^ (lane >> 3)) * 8;
    const u16* gA = X  + (size_t)(m0 + rowOff) * 1024 + colSw;
    const u16* gB = Wt + (size_t)(n0 + rowOff) * 1024 + colSw;
    u16* lA = As + wave * 2048;                    // 32 rows * 64 elems
    u16* lB = Bs + wave * 2048;

    // loop-invariant frag read offsets: chunk g=kh*4+quad stored at g^(l15&7)
    int swl = l15 & 7;
    int aB0 = (wm + l15) * 64 + ((quad ^ swl) * 8);
    int aB1 = (wm + l15) * 64 + (((4 + quad) ^ swl) * 8);
    int bB0 = (wn + l15) * 64 + ((quad ^ swl) * 8);
    int bB1 = (wn + l15) * 64 + (((4 + quad) ^ swl) * 8);

    for (int k0 = 0; k0 < 1024; k0 += 64) {
        __syncthreads();                            // prev tile consumed
        async16(gA + k0,             lA);
        async16(gA + k0 +  8 * 1024, lA + 512);
        async16(gA + k0 + 16 * 1024, lA + 1024);
        async16(gA + k0 + 24 * 1024, lA + 1536);
        async16(gB + k0,             lB);
        async16(gB + k0 +  8 * 1024, lB + 512);
        async16(gB + k0 + 16 * 1024, lB + 1024);
        async16(gB + k0 + 24 * 1024, lB + 1536);
        __syncthreads();                            // vmcnt(0) drain + barrier

        bf16x8 af[4][2], bf[4][2];
        for (int i = 0; i < 4; i++) {
            af[i][0] = *(const bf16x8*)(As + aB0 + i * 16 * 64);
            af[i][1] = *(const bf16x8*)(As + aB1 + i * 16 * 64);
        }
        for (int j = 0; j < 4; j++) {
            bf[j][0] = *(const bf16x8*)(Bs + bB0 + j * 16 * 64);
            bf[j][1] = *(const bf16x8*)(Bs + bB1 + j * 16 * 64);
        }
        for (int i = 0; i < 4; i++)
            for (int j = 0; j < 4; j++) {
                acc[i][j] = __builtin_amdgcn_mfma_f32_16x16x32_bf16(af[i][0], bf[j][0], acc[i][j], 0, 0, 0);
                acc[i][j] = __builtin_amdgcn_mfma_f32_16x16x32_bf16(af[i][1], bf[j][1], acc[i][j], 0, 0, 0);
            }
    }

    // epilogue: C[m][n], m = m0+wm+i*16+quad*4+r, n_col = n0+wn+j*16+l15
    const float QSC = 0.125f * 1.44269504f;        // folded scale*log2e for q
    for (int i = 0; i < 4; i++) {
        int gm   = m0 + wm + i * 16 + quad * 4;
        int b    = gm >> 11;                       // / 2048
        int nloc = gm & 2047;
        for (int j = 0; j < 4; j++) {
            int gn    = n0 + wn + j * 16 + l15;
            int which = gn >> 10;                  // 0=q 1=k 2=v (wave-uniform)
            int cc    = gn & 1023;
            int h     = cc >> 6;
            int d     = cc & 63;
            size_t bh = (size_t)(b * 16 + h);
            if (which == 2) {
                ushort4 w4;
                w4.x = f2b(acc[i][j][0]);
                w4.y = f2b(acc[i][j][1]);
                w4.z = f2b(acc[i][j][2]);
                w4.w = f2b(acc[i][j][3]);
                *(ushort4*)(vt + (bh * 64 + d) * 2048 + nloc) = w4;  // 4 consecutive n
            } else {
                u16* dst = (which == 0) ? q : k;
                float sc = (which == 0) ? QSC : 1.0f;
                for (int r = 0; r < 4; r++)
                    dst[(bh * 2048 + nloc + r) * 64 + d] = f2b(acc[i][j][r] * sc);
            }
        }
    }
}

// ---------------------------------------------------------------------------
// Kernel 4: flash attention — R15: P held in registers (no LDS round-trip).
// R14 post-mortem: LDS pipe ~82% busy (190 cyc/wave-tile vs 231 wall) — the
// binding pipe.  P-write(8 b64)+P-read(2 b128) = 72 cyc of that.
// Fix: MFMA's k index is a dummy — permute keys consistently in P and V:
//   kappa(quad*8+j) = (j>=4)*16 + quad*4 + (j&3)
// After QK^T, lane (quad,l15) ALREADY holds P[kappa(quad*8+j)][q=s*16+l15]
// = exactly the A-frag slot (m=l15, k=quad*8+j).  Pack in-register with
// cvt_pk (same 8/tile as before) -> pf feeds PV directly.  V's B-frag
// becomes two ds_read_b64 (keys 4q..4q+3 and 16+4q..+3, staging XOR
// respected) — same LDS pipe cost as the old b128.  Ones-MFMA denominator
// is permutation-invariant.  Ps buffer deleted: LDS 37.9 -> 27.6 KB.
// Falsifiers: absmax fails -> kappa mapping wrong -> revert attn; dur flat
// -> LDS wasn't binding -> re-profile.
// ---------------------------------------------------------------------------
__global__ __launch_bounds__(256, 4) void attn_kernel(const u16* __restrict__ q,
                                                      const u16* __restrict__ k,
                                                      const u16* __restrict__ vt,
                                                      const float* __restrict__ mask,
                                                      float* __restrict__ out) {
    __shared__ u16 Ks[3][32 * 64];    // [key][d]  linear, source-swizzled (12 KB)
    __shared__ u16 Vs[3][64 * 32];    // [d][key]  linear, source-swizzled (12 KB)
    __shared__ __align__(16) float Msr[3][256];    // mask tile ring (3 KB)

    int tid  = threadIdx.x;
    int wave = tid >> 6, lane = tid & 63, l15 = lane & 15, quad = lane >> 4;
    int bid = blockIdx.x;             // 1D: bh fastest -> XCD = bh%8 cluster
    int bh = bid & 63, qb = bid >> 6;
    int b = bh >> 4, h = bh & 15;
    size_t base = (size_t)bh * (N_ * 64);
    int q0 = qb * 128 + wave * 32;
    const float* mkb = mask + b * N_;

    // Q as B-operand fragments (q pre-scaled by 0.125*log2e at GEMM time)
    bf16x8 qf[2][2];
#pragma unroll
    for (int s = 0; s < 2; s++)
#pragma unroll
        for (int dc = 0; dc < 2; dc++)
            qf[s][dc] = *(const bf16x8*)(q + base + (size_t)(q0 + s * 16 + l15) * 64 + dc * 32 + quad * 8);

    const float L2E = 1.44269504f;
    float nmq[2];
    nmq[0] = -L2E * mkb[q0 + l15];
    nmq[1] = -L2E * mkb[q0 + 16 + l15];

    // all-ones B-fragment for the denominator MFMA
    bf16x8 onef;
#pragma unroll
    for (int i = 0; i < 8; i++) onef[i] = (__bf16)1.0f;

    floatx4 acc[2][4];                // [s][dt] PV accumulator
    floatx4 accl[2];                  // [s]     row-sum accumulator (denominator)
#pragma unroll
    for (int s = 0; s < 2; s++) {
        accl[s] = floatx4{0.f, 0.f, 0.f, 0.f};
#pragma unroll
        for (int dt = 0; dt < 4; dt++)
            acc[s][dt] = floatx4{0.f, 0.f, 0.f, 0.f};
    }

    // async16 staging, 1 K + 1 V + 1 M instr per wave per tile:
    //   K: 8 rows x 8 chunks;  wave w covers K rows [w*8,  w*8+8)
    //   V: 16 rows x 4 chunks; wave w covers V rows [w*16, w*16+16)
    //   M: 128 B mask tile, all waves duplicate (lane&7 source clamp)
    int krow = wave * 8  + (lane >> 3);
    int kcol = ((lane & 7) ^ (lane >> 3)) * 8;            // chunk ^ (r&7)
    int vrow = wave * 16 + (lane >> 2);
    int vcol = ((lane & 3) ^ ((lane >> 2) & 3)) * 8;      // chunk ^ (r&3)
    const u16* gK = k  + base + (size_t)krow * 64 + kcol;            // += kt*64
    const u16* gV = vt + ((size_t)bh * 64 + vrow) * 2048 + vcol;     // += kt
    const float* gM = mkb + (lane & 7) * 4;                          // += kt
    int wof = wave * 512;             // wave-uniform LDS stage offset

    // loop-invariant swizzled frag-read offsets
    int a0 = ((quad    ) ^ (l15 & 7)) * 8;    // K chunks 0..7  -> d = quad*8
    int a1 = ((4 + quad) ^ (l15 & 7)) * 8;    //                -> d = 32+quad*8
    // V b64 offsets (u16 units): chunk c stored at (c^(d&3)); d&3 == l15&3.
    //   b64#1: keys 4*quad..+3   = chunk (quad>>1),   half (quad&1)
    //   b64#2: keys 16+4*quad..+3 = chunk 2+(quad>>1), half (quad&1)
    int o1 = (((quad >> 1)    ) ^ (l15 & 3)) * 8 + (quad & 1) * 4;
    int o2 = (((quad >> 1) + 2) ^ (l15 & 3)) * 8 + (quad & 1) * 4;

    // one KVBLK=32 tile body; barrier + counted vmcnt(3) at TOP.
    auto TILE = [&](int kt, const u16* Kb, const u16* Vb, const float* Mb,
                    u16* Kn, u16* Vn, float* Mn) {
        asm volatile("s_waitcnt vmcnt(3)" ::: "memory");
        __builtin_amdgcn_s_barrier();
        __builtin_amdgcn_sched_barrier(0);
        int nkt = kt + 64; if (nkt > N_ - 32) nkt = N_ - 32;   // clamp (dead restage)
        async16(gK + (size_t)nkt * 64, Kn);
        async16(gV + nkt,              Vn);
        async16p(gM + nkt,             Mn);
        float4 mkv0 = *(const float4*)(Mb + quad * 4);
        float4 mkv1 = *(const float4*)(Mb + 16 + quad * 4);
        // S^T (key x q): C seeded with nmq*mk (mask add for free); p = exp2(S)
        float p[2][2][4];   // [s][t][r]: P[key = t*16 + quad*4 + r][q = s*16+l15]
#pragma unroll
        for (int t = 0; t < 2; t++) {
            bf16x8 kf0 = *(const bf16x8*)(Kb + (t * 16 + l15) * 64 + a0);
            bf16x8 kf1 = *(const bf16x8*)(Kb + (t * 16 + l15) * 64 + a1);
            float4 mk = t ? mkv1 : mkv0;
#pragma unroll
            for (int s = 0; s < 2; s++) {
                floatx4 sa;
                sa[0] = nmq[s] * mk.x;
                sa[1] = nmq[s] * mk.y;
                sa[2] = nmq[s] * mk.z;
                sa[3] = nmq[s] * mk.w;
                __builtin_amdgcn_s_setprio(1);
                sa = __builtin_amdgcn_mfma_f32_16x16x32_bf16(kf0, qf[s][0], sa, 0, 0, 0);
                sa = __builtin_amdgcn_mfma_f32_16x16x32_bf16(kf1, qf[s][1], sa, 0, 0, 0);
                __builtin_amdgcn_s_setprio(0);
                p[s][t][0] = fexp2(sa[0]);
                p[s][t][1] = fexp2(sa[1]);
                p[s][t][2] = fexp2(sa[2]);
                p[s][t][3] = fexp2(sa[3]);
            }
        }
        // pack P into A-fragments in-register (kappa order: j = t*4+r)
        bf16x8 pf[2];
#pragma unroll
        for (int s = 0; s < 2; s++) {
            uint4 u;
            u.x = pkraw(p[s][0][0], p[s][0][1]);
            u.y = pkraw(p[s][0][2], p[s][0][3]);
            u.z = pkraw(p[s][1][0], p[s][1][1]);
            u.w = pkraw(p[s][1][2], p[s][1][3]);
            __builtin_memcpy(&pf[s], &u, 16);
        }
        // denominator via ones-MFMA (permutation-invariant)
        __builtin_amdgcn_s_setprio(1);
        accl[0] = __builtin_amdgcn_mfma_f32_16x16x32_bf16(pf[0], onef, accl[0], 0, 0, 0);
        accl[1] = __builtin_amdgcn_mfma_f32_16x16x32_bf16(pf[1], onef, accl[1], 0, 0, 0);
        __builtin_amdgcn_s_setprio(0);
        // PV: vf assembled from two b64s in kappa key order
#pragma unroll
        for (int dt = 0; dt < 4; dt++) {
            const u16* vr = Vb + (dt * 16 + l15) * 32;
            uint2 v1 = *(const uint2*)(vr + o1);
            uint2 v2 = *(const uint2*)(vr + o2);
            uint4 vv; vv.x = v1.x; vv.y = v1.y; vv.z = v2.x; vv.w = v2.y;
            bf16x8 vf; __builtin_memcpy(&vf, &vv, 16);
            __builtin_amdgcn_s_setprio(1);
            acc[0][dt] = __builtin_amdgcn_mfma_f32_16x16x32_bf16(pf[0], vf, acc[0][dt], 0, 0, 0);
            acc[1][dt] = __builtin_amdgcn_mfma_f32_16x16x32_bf16(pf[1], vf, acc[1][dt], 0, 0, 0);
            __builtin_amdgcn_s_setprio(0);
        }
    };

    // prologue: drain qf/nmq loads so the vmcnt FIFO is clean, then stage
    // tiles 0,1 (3 ops each) and full-drain once.
    asm volatile("s_waitcnt vmcnt(0)" ::: "memory");
    async16(gK,            Ks[0] + wof);
    async16(gV,            Vs[0] + wof);
    async16p(gM,           Msr[0]);
    async16(gK + 32 * 64,  Ks[1] + wof);
    async16(gV + 32,       Vs[1] + wof);
    async16p(gM + 32,      Msr[1]);
    __syncthreads();

    // 64 tiles: 21 x 3 (ring-3, static buffers) + 1 tail
    for (int m = 0; m < 21; ++m) {
        int kt = m * 96;
        TILE(kt,      Ks[0], Vs[0], Msr[0], Ks[2] + wof, Vs[2] + wof, Msr[2]);
        TILE(kt + 32, Ks[1], Vs[1], Msr[1], Ks[0] + wof, Vs[0] + wof, Msr[0]);
        TILE(kt + 64, Ks[2], Vs[2], Msr[2], Ks[1] + wof, Vs[1] + wof, Msr[1]);
    }
    TILE(2016, Ks[0], Vs[0], Msr[0], Ks[2] + wof, Vs[2] + wof, Msr[2]);  // tile 63

    // epilogue: accl[s][r] = l(q = s*16+quad*4+r) — per-lane, no shuffles.
    // acc C-layout: col=l15=d, row=quad*4+r=q (same row-map as accl).
#pragma unroll
    for (int s = 0; s < 2; s++) {
#pragma unroll
        for (int r = 0; r < 4; r++) {
            float ir = 1.0f / accl[s][r];
            int qrow = q0 + s * 16 + quad * 4 + r;
            float* orow = out + ((size_t)(b * N_ + qrow)) * C_ + h * 64;
#pragma unroll
            for (int dt = 0; dt < 4; dt++)
                orow[dt * 16 + l15] = acc[s][dt][r] * ir;
        }
    }
}

// ---------------------------------------------------------------------------
extern "C" void kernel_launch(void* const* d_in, const int* in_sizes, int n_in,
                              void* d_out, int out_size, void* d_ws, size_t ws_size,
                              hipStream_t stream) {
    const float* inp  = (const float*)d_in[0];   // inputs  [B,N,C] fp32
    const float* mask = (const float*)d_in[1];   // mask    [B,N]   fp32
    const float* W    = (const float*)d_in[2];   // W_qkv   [C,3C]  fp32
    float* out = (float*)d_out;                  // [B,N,C] fp32

    char* ws = (char*)d_ws;
    u16* x  = (u16*)ws;                              // 16 MB  x=in+PE bf16
    u16* Wt = (u16*)(ws + 16777216);                 // 6 MB   W^T bf16
    u16* q  = (u16*)(ws + 23068672);                 // [B,H,N,64] bf16 (pre-scaled)
    u16* k  = q + 8388608;
    u16* vt = k + 8388608;                           // [B,H,64,N] bf16 (v transposed)

    pe_add_kernel<<<16384, 256, 0, stream>>>(inp, x);
    wt_kernel<<<dim3(96, 32), 256, 0, stream>>>(W, Wt);
    qkv_gemm_kernel<<<dim3(64, 24), 256, 0, stream>>>(x, Wt, q, k, vt);
    attn_kernel<<<1024, 256, 0, stream>>>(q, k, vt, mask, out);
}

// Round 15
// 230.791 us; speedup vs baseline: 1.0906x; 1.0060x over previous
//
#include <hip/hip_runtime.h>
#include <hip/hip_bf16.h>

typedef unsigned short u16;
typedef __bf16 bf16x8 __attribute__((ext_vector_type(8)));
typedef float floatx4 __attribute__((ext_vector_type(4)));

#define B_ 4
#define N_ 2048
#define C_ 1024
#define H_ 16
#define HD_ 64

__device__ __forceinline__ float b2f(u16 u) {
    union { float f; unsigned int i; } v; v.i = ((unsigned int)u) << 16; return v.f;
}
__device__ __forceinline__ u16 f2b(float f) {
    union { float f; unsigned int i; } v; v.f = f;
    unsigned int i = v.i;
    unsigned int r = i + 0x7FFFu + ((i >> 16) & 1u);
    return (u16)(r >> 16);
}
// hardware exp2 via BUILTIN (not inline asm): lowers to v_exp_f32 AND lets
// the backend insert the gfx950 trans-use wait state (R12 lesson: inline-asm
// producer hides the opcode from the hazard recognizer -> garbage).
__device__ __forceinline__ float fexp2(float x) {
    return __builtin_amdgcn_exp2f(x);
}
// packed f32->bf16 RNE, 1 VOP3 instr (R14-proven safe: not a trans op).
__device__ __forceinline__ unsigned int pkraw(float a, float b) {
    unsigned int u;
    asm("v_cvt_pk_bf16_f32 %0, %1, %2" : "=v"(u) : "v"(a), "v"(b));
    return u;
}
// async global->LDS, 16B per lane; LDS dest = wave-uniform base + lane*16
__device__ __forceinline__ void async16(const u16* g, u16* l) {
    __builtin_amdgcn_global_load_lds((const __attribute__((address_space(1))) unsigned int*)g,
                                     (__attribute__((address_space(3))) unsigned int*)l,
                                     16, 0, 0);
}
__device__ __forceinline__ void async16p(const void* g, void* l) {
    __builtin_amdgcn_global_load_lds((const __attribute__((address_space(1))) unsigned int*)g,
                                     (__attribute__((address_space(3))) unsigned int*)l,
                                     16, 0, 0);
}

// ---------------------------------------------------------------------------
// Kernel 1: x = inputs(fp32) + sinusoidal PE  ->  bf16 x.
// ---------------------------------------------------------------------------
__global__ __launch_bounds__(256) void pe_add_kernel(const float* __restrict__ in,
                                                     u16* __restrict__ x) {
    int idx = blockIdx.x * 256 + threadIdx.x;      // pair index, total B*N*C/2
    int cp  = idx & 511;                            // C/2 = 512 pairs per row
    int row = idx >> 9;                             // b*N + n
    int n   = row & (N_ - 1);
    float r = exp2f(-13.287712379549449f * ((float)cp * (1.0f / 512.0f)));
    float ang = (float)n * r;
    float s, c;
    sincosf(ang, &s, &c);
    float2 pr = ((const float2*)in)[idx];
    unsigned int o = ((unsigned int)f2b(pr.y + c) << 16) | (unsigned int)f2b(pr.x + s);
    ((unsigned int*)x)[idx] = o;
}

// ---------------------------------------------------------------------------
// Kernel 2: transpose W_qkv fp32 [1024][3072] -> bf16 Wt [3072][1024].
// ---------------------------------------------------------------------------
__global__ __launch_bounds__(256) void wt_kernel(const float* __restrict__ W,
                                                 u16* __restrict__ Wt) {
    __shared__ u16 tile[32][33];
    int bx = blockIdx.x;            // over 3072/32 = 96
    int by = blockIdx.y;            // over 1024/32 = 32
    int tx = threadIdx.x & 31;
    int ty = threadIdx.x >> 5;      // 0..7
    for (int i = 0; i < 32; i += 8)
        tile[ty + i][tx] = f2b(W[(size_t)(by * 32 + ty + i) * 3072 + bx * 32 + tx]);
    __syncthreads();
    for (int i = 0; i < 32; i += 8)
        Wt[(size_t)(bx * 32 + ty + i) * 1024 + by * 32 + tx] = tile[tx][ty + i];
}

// ---------------------------------------------------------------------------
// Kernel 3: QKV GEMM, BK=64 — R13 grid (dim3(64,24)), proven best.
// ---------------------------------------------------------------------------
__global__ __launch_bounds__(256) void qkv_gemm_kernel(const u16* __restrict__ X,
                                                       const u16* __restrict__ Wt,
                                                       u16* __restrict__ q,
                                                       u16* __restrict__ k,
                                                       u16* __restrict__ vt) {
    __shared__ u16 As[128 * 64];
    __shared__ u16 Bs[128 * 64];
    int tid  = threadIdx.x;
    int wave = tid >> 6, lane = tid & 63, l15 = lane & 15, quad = lane >> 4;
    int m0 = blockIdx.x * 128;
    int n0 = blockIdx.y * 128;
    int wm = (wave & 1) * 64;
    int wn = (wave >> 1) * 64;

    floatx4 acc[4][4];
    for (int i = 0; i < 4; i++)
        for (int j = 0; j < 4; j++)
            acc[i][j] = floatx4{0.f, 0.f, 0.f, 0.f};

    // staging: wave stages rows [wave*32, wave*32+32), 4 instrs of 8 rows each.
    // LDS[r][c'] = global[r][c' ^ (r&7)]  (c' = lane&7, r&7 = lane>>3)
    int rowOff = wave * 32 + (lane >> 3);
    int colSw  = ((lane & 7) ^ (lane >> 3)) * 8;
    const u16* gA = X  + (size_t)(m0 + rowOff) * 1024 + colSw;
    const u16* gB = Wt + (size_t)(n0 + rowOff) * 1024 + colSw;
    u16* lA = As + wave * 2048;                    // 32 rows * 64 elems
    u16* lB = Bs + wave * 2048;

    // loop-invariant frag read offsets: chunk g=kh*4+quad stored at g^(l15&7)
    int swl = l15 & 7;
    int aB0 = (wm + l15) * 64 + ((quad ^ swl) * 8);
    int aB1 = (wm + l15) * 64 + (((4 + quad) ^ swl) * 8);
    int bB0 = (wn + l15) * 64 + ((quad ^ swl) * 8);
    int bB1 = (wn + l15) * 64 + (((4 + quad) ^ swl) * 8);

    for (int k0 = 0; k0 < 1024; k0 += 64) {
        __syncthreads();                            // prev tile consumed
        async16(gA + k0,             lA);
        async16(gA + k0 +  8 * 1024, lA + 512);
        async16(gA + k0 + 16 * 1024, lA + 1024);
        async16(gA + k0 + 24 * 1024, lA + 1536);
        async16(gB + k0,             lB);
        async16(gB + k0 +  8 * 1024, lB + 512);
        async16(gB + k0 + 16 * 1024, lB + 1024);
        async16(gB + k0 + 24 * 1024, lB + 1536);
        __syncthreads();                            // vmcnt(0) drain + barrier

        bf16x8 af[4][2], bf[4][2];
        for (int i = 0; i < 4; i++) {
            af[i][0] = *(const bf16x8*)(As + aB0 + i * 16 * 64);
            af[i][1] = *(const bf16x8*)(As + aB1 + i * 16 * 64);
        }
        for (int j = 0; j < 4; j++) {
            bf[j][0] = *(const bf16x8*)(Bs + bB0 + j * 16 * 64);
            bf[j][1] = *(const bf16x8*)(Bs + bB1 + j * 16 * 64);
        }
        for (int i = 0; i < 4; i++)
            for (int j = 0; j < 4; j++) {
                acc[i][j] = __builtin_amdgcn_mfma_f32_16x16x32_bf16(af[i][0], bf[j][0], acc[i][j], 0, 0, 0);
                acc[i][j] = __builtin_amdgcn_mfma_f32_16x16x32_bf16(af[i][1], bf[j][1], acc[i][j], 0, 0, 0);
            }
    }

    // epilogue: C[m][n], m = m0+wm+i*16+quad*4+r, n_col = n0+wn+j*16+l15
    const float QSC = 0.125f * 1.44269504f;        // folded scale*log2e for q
    for (int i = 0; i < 4; i++) {
        int gm   = m0 + wm + i * 16 + quad * 4;
        int b    = gm >> 11;                       // / 2048
        int nloc = gm & 2047;
        for (int j = 0; j < 4; j++) {
            int gn    = n0 + wn + j * 16 + l15;
            int which = gn >> 10;                  // 0=q 1=k 2=v (wave-uniform)
            int cc    = gn & 1023;
            int h     = cc >> 6;
            int d     = cc & 63;
            size_t bh = (size_t)(b * 16 + h);
            if (which == 2) {
                ushort4 w4;
                w4.x = f2b(acc[i][j][0]);
                w4.y = f2b(acc[i][j][1]);
                w4.z = f2b(acc[i][j][2]);
                w4.w = f2b(acc[i][j][3]);
                *(ushort4*)(vt + (bh * 64 + d) * 2048 + nloc) = w4;  // 4 consecutive n
            } else {
                u16* dst = (which == 0) ? q : k;
                float sc = (which == 0) ? QSC : 1.0f;
                for (int r = 0; r < 4; r++)
                    dst[(bh * 2048 + nloc + r) * 64 + d] = f2b(acc[i][j][r] * sc);
            }
        }
    }
}

// ---------------------------------------------------------------------------
// Kernel 4: flash attention — R16: V bank-conflict fix (deeper XOR swizzle).
// R15 post-mortem: 86.7 us, LDS ~75% busy, BANK_CONFLICT 12.58M = 24% of
// wall cycles/CU.  Source: V b64 reads — Vs rows are 64B (half bank-wrap),
// so rows 4 apart alias (mod 128B); lanes {0,4,8,12} of each quad land on
// the same bank pair -> 4-way conflict per 16-lane b64 issue group, on all
// 8 V-reads/tile.  K reads are conflict-free (128B rows, sequential-lane
// chunk spread); M reads are broadcasts.
// Fix (rule #21, both-sides-or-neither): add the (row>>2)&3 term to the V
// XOR on BOTH the staging source and the read offsets:
//   stage: vcol = ((lane&3) ^ ((lane>>2)&3) ^ ((lane>>4)&3)) * 8
//   read:  o1/o2 = (chunk ^ (l15&3) ^ ((l15>>2)&3))*8 + (quad&1)*4
// ((d>>2)&3 == (l15>>2)&3 since dt*4 = 0 mod 4 -> still loop/dt-invariant.)
// Per-16-lane-group banks now 2-way max (free, m136).
// Falsifier: conflicts drop but dur flat -> conflicts off critical path ->
// attn near structural floor -> pivot to GEMM next round.
// ---------------------------------------------------------------------------
__global__ __launch_bounds__(256, 4) void attn_kernel(const u16* __restrict__ q,
                                                      const u16* __restrict__ k,
                                                      const u16* __restrict__ vt,
                                                      const float* __restrict__ mask,
                                                      float* __restrict__ out) {
    __shared__ u16 Ks[3][32 * 64];    // [key][d]  linear, source-swizzled (12 KB)
    __shared__ u16 Vs[3][64 * 32];    // [d][key]  linear, source-swizzled (12 KB)
    __shared__ __align__(16) float Msr[3][256];    // mask tile ring (3 KB)

    int tid  = threadIdx.x;
    int wave = tid >> 6, lane = tid & 63, l15 = lane & 15, quad = lane >> 4;
    int bid = blockIdx.x;             // 1D: bh fastest -> XCD = bh%8 cluster
    int bh = bid & 63, qb = bid >> 6;
    int b = bh >> 4, h = bh & 15;
    size_t base = (size_t)bh * (N_ * 64);
    int q0 = qb * 128 + wave * 32;
    const float* mkb = mask + b * N_;

    // Q as B-operand fragments (q pre-scaled by 0.125*log2e at GEMM time)
    bf16x8 qf[2][2];
#pragma unroll
    for (int s = 0; s < 2; s++)
#pragma unroll
        for (int dc = 0; dc < 2; dc++)
            qf[s][dc] = *(const bf16x8*)(q + base + (size_t)(q0 + s * 16 + l15) * 64 + dc * 32 + quad * 8);

    const float L2E = 1.44269504f;
    float nmq[2];
    nmq[0] = -L2E * mkb[q0 + l15];
    nmq[1] = -L2E * mkb[q0 + 16 + l15];

    // all-ones B-fragment for the denominator MFMA
    bf16x8 onef;
#pragma unroll
    for (int i = 0; i < 8; i++) onef[i] = (__bf16)1.0f;

    floatx4 acc[2][4];                // [s][dt] PV accumulator
    floatx4 accl[2];                  // [s]     row-sum accumulator (denominator)
#pragma unroll
    for (int s = 0; s < 2; s++) {
        accl[s] = floatx4{0.f, 0.f, 0.f, 0.f};
#pragma unroll
        for (int dt = 0; dt < 4; dt++)
            acc[s][dt] = floatx4{0.f, 0.f, 0.f, 0.f};
    }

    // async16 staging, 1 K + 1 V + 1 M instr per wave per tile:
    //   K: 8 rows x 8 chunks;  wave w covers K rows [w*8,  w*8+8)
    //   V: 16 rows x 4 chunks; wave w covers V rows [w*16, w*16+16)
    //   M: 128 B mask tile, all waves duplicate (lane&7 source clamp)
    int krow = wave * 8  + (lane >> 3);
    int kcol = ((lane & 7) ^ (lane >> 3)) * 8;            // chunk ^ (r&7)
    int vrow = wave * 16 + (lane >> 2);
    int vcol = ((lane & 3) ^ ((lane >> 2) & 3) ^ ((lane >> 4) & 3)) * 8;  // chunk ^ (r&3) ^ ((r>>2)&3)
    const u16* gK = k  + base + (size_t)krow * 64 + kcol;            // += kt*64
    const u16* gV = vt + ((size_t)bh * 64 + vrow) * 2048 + vcol;     // += kt
    const float* gM = mkb + (lane & 7) * 4;                          // += kt
    int wof = wave * 512;             // wave-uniform LDS stage offset

    // loop-invariant swizzled frag-read offsets
    int a0 = ((quad    ) ^ (l15 & 7)) * 8;    // K chunks 0..7  -> d = quad*8
    int a1 = ((4 + quad) ^ (l15 & 7)) * 8;    //                -> d = 32+quad*8
    // V b64 offsets (u16 units): chunk c stored at c ^ (d&3) ^ ((d>>2)&3);
    // d&3 == l15&3, (d>>2)&3 == (l15>>2)&3 (dt-invariant).
    //   b64#1: keys 4*quad..+3    = chunk (quad>>1),   half (quad&1)
    //   b64#2: keys 16+4*quad..+3 = chunk 2+(quad>>1), half (quad&1)
    int vsw = (l15 & 3) ^ ((l15 >> 2) & 3);
    int o1 = (((quad >> 1)    ) ^ vsw) * 8 + (quad & 1) * 4;
    int o2 = (((quad >> 1) + 2) ^ vsw) * 8 + (quad & 1) * 4;

    // one KVBLK=32 tile body; barrier + counted vmcnt(3) at TOP.
    auto TILE = [&](int kt, const u16* Kb, const u16* Vb, const float* Mb,
                    u16* Kn, u16* Vn, float* Mn) {
        asm volatile("s_waitcnt vmcnt(3)" ::: "memory");
        __builtin_amdgcn_s_barrier();
        __builtin_amdgcn_sched_barrier(0);
        int nkt = kt + 64; if (nkt > N_ - 32) nkt = N_ - 32;   // clamp (dead restage)
        async16(gK + (size_t)nkt * 64, Kn);
        async16(gV + nkt,              Vn);
        async16p(gM + nkt,             Mn);
        float4 mkv0 = *(const float4*)(Mb + quad * 4);
        float4 mkv1 = *(const float4*)(Mb + 16 + quad * 4);
        // S^T (key x q): C seeded with nmq*mk (mask add for free); p = exp2(S)
        float p[2][2][4];   // [s][t][r]: P[key = t*16 + quad*4 + r][q = s*16+l15]
#pragma unroll
        for (int t = 0; t < 2; t++) {
            bf16x8 kf0 = *(const bf16x8*)(Kb + (t * 16 + l15) * 64 + a0);
            bf16x8 kf1 = *(const bf16x8*)(Kb + (t * 16 + l15) * 64 + a1);
            float4 mk = t ? mkv1 : mkv0;
#pragma unroll
            for (int s = 0; s < 2; s++) {
                floatx4 sa;
                sa[0] = nmq[s] * mk.x;
                sa[1] = nmq[s] * mk.y;
                sa[2] = nmq[s] * mk.z;
                sa[3] = nmq[s] * mk.w;
                __builtin_amdgcn_s_setprio(1);
                sa = __builtin_amdgcn_mfma_f32_16x16x32_bf16(kf0, qf[s][0], sa, 0, 0, 0);
                sa = __builtin_amdgcn_mfma_f32_16x16x32_bf16(kf1, qf[s][1], sa, 0, 0, 0);
                __builtin_amdgcn_s_setprio(0);
                p[s][t][0] = fexp2(sa[0]);
                p[s][t][1] = fexp2(sa[1]);
                p[s][t][2] = fexp2(sa[2]);
                p[s][t][3] = fexp2(sa[3]);
            }
        }
        // pack P into A-fragments in-register (kappa order: j = t*4+r)
        bf16x8 pf[2];
#pragma unroll
        for (int s = 0; s < 2; s++) {
            uint4 u;
            u.x = pkraw(p[s][0][0], p[s][0][1]);
            u.y = pkraw(p[s][0][2], p[s][0][3]);
            u.z = pkraw(p[s][1][0], p[s][1][1]);
            u.w = pkraw(p[s][1][2], p[s][1][3]);
            __builtin_memcpy(&pf[s], &u, 16);
        }
        // denominator via ones-MFMA (permutation-invariant)
        __builtin_amdgcn_s_setprio(1);
        accl[0] = __builtin_amdgcn_mfma_f32_16x16x32_bf16(pf[0], onef, accl[0], 0, 0, 0);
        accl[1] = __builtin_amdgcn_mfma_f32_16x16x32_bf16(pf[1], onef, accl[1], 0, 0, 0);
        __builtin_amdgcn_s_setprio(0);
        // PV: vf assembled from two b64s in kappa key order
#pragma unroll
        for (int dt = 0; dt < 4; dt++) {
            const u16* vr = Vb + (dt * 16 + l15) * 32;
            uint2 v1 = *(const uint2*)(vr + o1);
            uint2 v2 = *(const uint2*)(vr + o2);
            uint4 vv; vv.x = v1.x; vv.y = v1.y; vv.z = v2.x; vv.w = v2.y;
            bf16x8 vf; __builtin_memcpy(&vf, &vv, 16);
            __builtin_amdgcn_s_setprio(1);
            acc[0][dt] = __builtin_amdgcn_mfma_f32_16x16x32_bf16(pf[0], vf, acc[0][dt], 0, 0, 0);
            acc[1][dt] = __builtin_amdgcn_mfma_f32_16x16x32_bf16(pf[1], vf, acc[1][dt], 0, 0, 0);
            __builtin_amdgcn_s_setprio(0);
        }
    };

    // prologue: drain qf/nmq loads so the vmcnt FIFO is clean, then stage
    // tiles 0,1 (3 ops each) and full-drain once.
    asm volatile("s_waitcnt vmcnt(0)" ::: "memory");
    async16(gK,            Ks[0] + wof);
    async16(gV,            Vs[0] + wof);
    async16p(gM,           Msr[0]);
    async16(gK + 32 * 64,  Ks[1] + wof);
    async16(gV + 32,       Vs[1] + wof);
    async16p(gM + 32,      Msr[1]);
    __syncthreads();

    // 64 tiles: 21 x 3 (ring-3, static buffers) + 1 tail
    for (int m = 0; m < 21; ++m) {
        int kt = m * 96;
        TILE(kt,      Ks[0], Vs[0], Msr[0], Ks[2] + wof, Vs[2] + wof, Msr[2]);
        TILE(kt + 32, Ks[1], Vs[1], Msr[1], Ks[0] + wof, Vs[0] + wof, Msr[0]);
        TILE(kt + 64, Ks[2], Vs[2], Msr[2], Ks[1] + wof, Vs[1] + wof, Msr[1]);
    }
    TILE(2016, Ks[0], Vs[0], Msr[0], Ks[2] + wof, Vs[2] + wof, Msr[2]);  // tile 63

    // epilogue: accl[s][r] = l(q = s*16+quad*4+r) — per-lane, no shuffles.
    // acc C-layout: col=l15=d, row=quad*4+r=q (same row-map as accl).
#pragma unroll
    for (int s = 0; s < 2; s++) {
#pragma unroll
        for (int r = 0; r < 4; r++) {
            float ir = 1.0f / accl[s][r];
            int qrow = q0 + s * 16 + quad * 4 + r;
            float* orow = out + ((size_t)(b * N_ + qrow)) * C_ + h * 64;
#pragma unroll
            for (int dt = 0; dt < 4; dt++)
                orow[dt * 16 + l15] = acc[s][dt][r] * ir;
        }
    }
}

// ---------------------------------------------------------------------------
extern "C" void kernel_launch(void* const* d_in, const int* in_sizes, int n_in,
                              void* d_out, int out_size, void* d_ws, size_t ws_size,
                              hipStream_t stream) {
    const float* inp  = (const float*)d_in[0];   // inputs  [B,N,C] fp32
    const float* mask = (const float*)d_in[1];   // mask    [B,N]   fp32
    const float* W    = (const float*)d_in[2];   // W_qkv   [C,3C]  fp32
    float* out = (float*)d_out;                  // [B,N,C] fp32

    char* ws = (char*)d_ws;
    u16* x  = (u16*)ws;                              // 16 MB  x=in+PE bf16
    u16* Wt = (u16*)(ws + 16777216);                 // 6 MB   W^T bf16
    u16* q  = (u16*)(ws + 23068672);                 // [B,H,N,64] bf16 (pre-scaled)
    u16* k  = q + 8388608;
    u16* vt = k + 8388608;                           // [B,H,64,N] bf16 (v transposed)

    pe_add_kernel<<<16384, 256, 0, stream>>>(inp, x);
    wt_kernel<<<dim3(96, 32), 256, 0, stream>>>(W, Wt);
    qkv_gemm_kernel<<<dim3(64, 24), 256, 0, stream>>>(x, Wt, q, k, vt);
    attn_kernel<<<1024, 256, 0, stream>>>(q, k, vt, mask, out);
}

// Round 16
// 229.883 us; speedup vs baseline: 1.0949x; 1.0039x over previous
//
#include <hip/hip_runtime.h>
#include <hip/hip_bf16.h>

typedef unsigned short u16;
typedef __bf16 bf16x8 __attribute__((ext_vector_type(8)));
typedef float floatx4 __attribute__((ext_vector_type(4)));

#define B_ 4
#define N_ 2048
#define C_ 1024
#define H_ 16
#define HD_ 64

__device__ __forceinline__ float b2f(u16 u) {
    union { float f; unsigned int i; } v; v.i = ((unsigned int)u) << 16; return v.f;
}
__device__ __forceinline__ u16 f2b(float f) {
    union { float f; unsigned int i; } v; v.f = f;
    unsigned int i = v.i;
    unsigned int r = i + 0x7FFFu + ((i >> 16) & 1u);
    return (u16)(r >> 16);
}
// hardware exp2 via BUILTIN (not inline asm): R12 lesson — trans-op via asm
// hides the producer opcode from the hazard recognizer -> garbage.
__device__ __forceinline__ float fexp2(float x) {
    return __builtin_amdgcn_exp2f(x);
}
// packed f32->bf16 RNE, 1 VOP3 instr (R14-proven safe: not a trans op).
__device__ __forceinline__ unsigned int pkraw(float a, float b) {
    unsigned int u;
    asm("v_cvt_pk_bf16_f32 %0, %1, %2" : "=v"(u) : "v"(a), "v"(b));
    return u;
}
// async global->LDS, 16B per lane; LDS dest = wave-uniform base + lane*16
__device__ __forceinline__ void async16(const u16* g, u16* l) {
    __builtin_amdgcn_global_load_lds((const __attribute__((address_space(1))) unsigned int*)g,
                                     (__attribute__((address_space(3))) unsigned int*)l,
                                     16, 0, 0);
}
__device__ __forceinline__ void async16p(const void* g, void* l) {
    __builtin_amdgcn_global_load_lds((const __attribute__((address_space(1))) unsigned int*)g,
                                     (__attribute__((address_space(3))) unsigned int*)l,
                                     16, 0, 0);
}

// ---------------------------------------------------------------------------
// Kernel 1: x = inputs(fp32) + sinusoidal PE  ->  bf16 x.
// R17: sincosf(ang) with ang up to ~2047 rad hit OCML's Payne-Hanek slow
// path (divergent, hundreds of instrs x 4.2M threads).  Native __sinf/__cosf
// (v_sin_f32, compiler-handled reduction + trans hazard) err ~7.5e-4 << bf16
// grain (2^-8) and << absmax threshold.
// ---------------------------------------------------------------------------
__global__ __launch_bounds__(256) void pe_add_kernel(const float* __restrict__ in,
                                                     u16* __restrict__ x) {
    int idx = blockIdx.x * 256 + threadIdx.x;      // pair index, total B*N*C/2
    int cp  = idx & 511;                            // C/2 = 512 pairs per row
    int row = idx >> 9;                             // b*N + n
    int n   = row & (N_ - 1);
    float r = fexp2(-13.287712379549449f * ((float)cp * (1.0f / 512.0f)));
    float ang = (float)n * r;
    float s = __sinf(ang);
    float c = __cosf(ang);
    float2 pr = ((const float2*)in)[idx];
    unsigned int o = ((unsigned int)f2b(pr.y + c) << 16) | (unsigned int)f2b(pr.x + s);
    ((unsigned int*)x)[idx] = o;
}

// ---------------------------------------------------------------------------
// Kernel 2: transpose W_qkv fp32 [1024][3072] -> bf16 Wt [3072][1024].
// ---------------------------------------------------------------------------
__global__ __launch_bounds__(256) void wt_kernel(const float* __restrict__ W,
                                                 u16* __restrict__ Wt) {
    __shared__ u16 tile[32][33];
    int bx = blockIdx.x;            // over 3072/32 = 96
    int by = blockIdx.y;            // over 1024/32 = 32
    int tx = threadIdx.x & 31;
    int ty = threadIdx.x >> 5;      // 0..7
    for (int i = 0; i < 32; i += 8)
        tile[ty + i][tx] = f2b(W[(size_t)(by * 32 + ty + i) * 3072 + bx * 32 + tx]);
    __syncthreads();
    for (int i = 0; i < 32; i += 8)
        Wt[(size_t)(bx * 32 + ty + i) * 1024 + by * 32 + tx] = tile[tx][ty + i];
}

// ---------------------------------------------------------------------------
// Kernel 3: QKV GEMM — R17: ring-2 counted-vmcnt pipeline (attn-R11 recipe).
// Old structure staged AND drained (vmcnt 0) inside the same barrier pair:
// zero prefetch depth — the m97 ~20% drain stall.  New: stage tile t+1 into
// the other buffer BEFORE waiting vmcnt(8) for tile t; loads stay in flight
// across the barrier with a full 32-MFMA phase (~620 cyc) to land.
// Race audit: stage(t+1)->buf[(t+1)&1] last read at body t-1, sealed by its
// end barrier; vmcnt FIFO 16 outstanding -> vmcnt(8) = exactly tile t done;
// barrier then publishes all waves' rows.  Tail stages a clamped dead tile
// to keep counts uniform.  LDS 64 KB -> 2 blocks/CU; the 2 co-resident
// blocks give each SIMD 2 independent-barrier waves for overlap.
// Layout / frag reads / epilogue unchanged (proven conflict-free).
// ---------------------------------------------------------------------------
__global__ __launch_bounds__(256) void qkv_gemm_kernel(const u16* __restrict__ X,
                                                       const u16* __restrict__ Wt,
                                                       u16* __restrict__ q,
                                                       u16* __restrict__ k,
                                                       u16* __restrict__ vt) {
    __shared__ u16 As0[128 * 64];
    __shared__ u16 As1[128 * 64];
    __shared__ u16 Bs0[128 * 64];
    __shared__ u16 Bs1[128 * 64];
    int tid  = threadIdx.x;
    int wave = tid >> 6, lane = tid & 63, l15 = lane & 15, quad = lane >> 4;
    int m0 = blockIdx.x * 128;
    int n0 = blockIdx.y * 128;
    int wm = (wave & 1) * 64;
    int wn = (wave >> 1) * 64;

    floatx4 acc[4][4];
    for (int i = 0; i < 4; i++)
        for (int j = 0; j < 4; j++)
            acc[i][j] = floatx4{0.f, 0.f, 0.f, 0.f};

    // staging: wave stages rows [wave*32, wave*32+32), 4 instrs of 8 rows each.
    // LDS[r][c'] = global[r][c' ^ (r&7)]  (c' = lane&7, r&7 = lane>>3)
    int rowOff = wave * 32 + (lane >> 3);
    int colSw  = ((lane & 7) ^ (lane >> 3)) * 8;
    const u16* gA = X  + (size_t)(m0 + rowOff) * 1024 + colSw;
    const u16* gB = Wt + (size_t)(n0 + rowOff) * 1024 + colSw;
    int wof = wave * 2048;                          // 32 rows * 64 elems

    // loop-invariant frag read offsets: chunk g=kh*4+quad stored at g^(l15&7)
    int swl = l15 & 7;
    int aB0 = (wm + l15) * 64 + ((quad ^ swl) * 8);
    int aB1 = (wm + l15) * 64 + (((4 + quad) ^ swl) * 8);
    int bB0 = (wn + l15) * 64 + ((quad ^ swl) * 8);
    int bB1 = (wn + l15) * 64 + (((4 + quad) ^ swl) * 8);

    auto STAGE = [&](int k0, u16* A, u16* B) {
        async16(gA + k0,             A + wof);
        async16(gA + k0 +  8 * 1024, A + wof + 512);
        async16(gA + k0 + 16 * 1024, A + wof + 1024);
        async16(gA + k0 + 24 * 1024, A + wof + 1536);
        async16(gB + k0,             B + wof);
        async16(gB + k0 +  8 * 1024, B + wof + 512);
        async16(gB + k0 + 16 * 1024, B + wof + 1024);
        async16(gB + k0 + 24 * 1024, B + wof + 1536);
    };
    auto COMPUTE = [&](const u16* A, const u16* B) {
        bf16x8 af[4][2], bf[4][2];
#pragma unroll
        for (int i = 0; i < 4; i++) {
            af[i][0] = *(const bf16x8*)(A + aB0 + i * 1024);
            af[i][1] = *(const bf16x8*)(A + aB1 + i * 1024);
        }
#pragma unroll
        for (int j = 0; j < 4; j++) {
            bf[j][0] = *(const bf16x8*)(B + bB0 + j * 1024);
            bf[j][1] = *(const bf16x8*)(B + bB1 + j * 1024);
        }
#pragma unroll
        for (int i = 0; i < 4; i++)
#pragma unroll
            for (int j = 0; j < 4; j++) {
                acc[i][j] = __builtin_amdgcn_mfma_f32_16x16x32_bf16(af[i][0], bf[j][0], acc[i][j], 0, 0, 0);
                acc[i][j] = __builtin_amdgcn_mfma_f32_16x16x32_bf16(af[i][1], bf[j][1], acc[i][j], 0, 0, 0);
            }
    };

    STAGE(0, As0, Bs0);                             // prologue: tile 0 in flight
    for (int t = 0; t < 16; t += 2) {
        STAGE((t + 1) * 64, As1, Bs1);              // t+1 <= 15 always
        asm volatile("s_waitcnt vmcnt(8)" ::: "memory");
        __builtin_amdgcn_s_barrier();
        __builtin_amdgcn_sched_barrier(0);
        COMPUTE(As0, Bs0);
        __builtin_amdgcn_s_barrier();               // all reads of As0/Bs0 done
        int k2 = (t + 2 < 16) ? (t + 2) * 64 : 960; // tail: dead restage
        STAGE(k2, As0, Bs0);
        asm volatile("s_waitcnt vmcnt(8)" ::: "memory");
        __builtin_amdgcn_s_barrier();
        __builtin_amdgcn_sched_barrier(0);
        COMPUTE(As1, Bs1);
        __builtin_amdgcn_s_barrier();               // all reads of As1/Bs1 done
    }

    // epilogue: C[m][n], m = m0+wm+i*16+quad*4+r, n_col = n0+wn+j*16+l15
    const float QSC = 0.125f * 1.44269504f;        // folded scale*log2e for q
    for (int i = 0; i < 4; i++) {
        int gm   = m0 + wm + i * 16 + quad * 4;
        int b    = gm >> 11;                       // / 2048
        int nloc = gm & 2047;
        for (int j = 0; j < 4; j++) {
            int gn    = n0 + wn + j * 16 + l15;
            int which = gn >> 10;                  // 0=q 1=k 2=v (wave-uniform)
            int cc    = gn & 1023;
            int h     = cc >> 6;
            int d     = cc & 63;
            size_t bh = (size_t)(b * 16 + h);
            if (which == 2) {
                ushort4 w4;
                w4.x = f2b(acc[i][j][0]);
                w4.y = f2b(acc[i][j][1]);
                w4.z = f2b(acc[i][j][2]);
                w4.w = f2b(acc[i][j][3]);
                *(ushort4*)(vt + (bh * 64 + d) * 2048 + nloc) = w4;  // 4 consecutive n
            } else {
                u16* dst = (which == 0) ? q : k;
                float sc = (which == 0) ? QSC : 1.0f;
                for (int r = 0; r < 4; r++)
                    dst[(bh * 2048 + nloc + r) * 64 + d] = f2b(acc[i][j][r] * sc);
            }
        }
    }
}

// ---------------------------------------------------------------------------
// Kernel 4: flash attention — R16 (FROZEN: 84.1 us, conflicts 0, absmax ok).
// ---------------------------------------------------------------------------
__global__ __launch_bounds__(256, 4) void attn_kernel(const u16* __restrict__ q,
                                                      const u16* __restrict__ k,
                                                      const u16* __restrict__ vt,
                                                      const float* __restrict__ mask,
                                                      float* __restrict__ out) {
    __shared__ u16 Ks[3][32 * 64];    // [key][d]  linear, source-swizzled (12 KB)
    __shared__ u16 Vs[3][64 * 32];    // [d][key]  linear, source-swizzled (12 KB)
    __shared__ __align__(16) float Msr[3][256];    // mask tile ring (3 KB)

    int tid  = threadIdx.x;
    int wave = tid >> 6, lane = tid & 63, l15 = lane & 15, quad = lane >> 4;
    int bid = blockIdx.x;             // 1D: bh fastest -> XCD = bh%8 cluster
    int bh = bid & 63, qb = bid >> 6;
    int b = bh >> 4, h = bh & 15;
    size_t base = (size_t)bh * (N_ * 64);
    int q0 = qb * 128 + wave * 32;
    const float* mkb = mask + b * N_;

    // Q as B-operand fragments (q pre-scaled by 0.125*log2e at GEMM time)
    bf16x8 qf[2][2];
#pragma unroll
    for (int s = 0; s < 2; s++)
#pragma unroll
        for (int dc = 0; dc < 2; dc++)
            qf[s][dc] = *(const bf16x8*)(q + base + (size_t)(q0 + s * 16 + l15) * 64 + dc * 32 + quad * 8);

    const float L2E = 1.44269504f;
    float nmq[2];
    nmq[0] = -L2E * mkb[q0 + l15];
    nmq[1] = -L2E * mkb[q0 + 16 + l15];

    // all-ones B-fragment for the denominator MFMA
    bf16x8 onef;
#pragma unroll
    for (int i = 0; i < 8; i++) onef[i] = (__bf16)1.0f;

    floatx4 acc[2][4];                // [s][dt] PV accumulator
    floatx4 accl[2];                  // [s]     row-sum accumulator (denominator)
#pragma unroll
    for (int s = 0; s < 2; s++) {
        accl[s] = floatx4{0.f, 0.f, 0.f, 0.f};
#pragma unroll
        for (int dt = 0; dt < 4; dt++)
            acc[s][dt] = floatx4{0.f, 0.f, 0.f, 0.f};
    }

    // async16 staging, 1 K + 1 V + 1 M instr per wave per tile:
    //   K: 8 rows x 8 chunks;  wave w covers K rows [w*8,  w*8+8)
    //   V: 16 rows x 4 chunks; wave w covers V rows [w*16, w*16+16)
    //   M: 128 B mask tile, all waves duplicate (lane&7 source clamp)
    int krow = wave * 8  + (lane >> 3);
    int kcol = ((lane & 7) ^ (lane >> 3)) * 8;            // chunk ^ (r&7)
    int vrow = wave * 16 + (lane >> 2);
    int vcol = ((lane & 3) ^ ((lane >> 2) & 3) ^ ((lane >> 4) & 3)) * 8;  // chunk ^ (r&3) ^ ((r>>2)&3)
    const u16* gK = k  + base + (size_t)krow * 64 + kcol;            // += kt*64
    const u16* gV = vt + ((size_t)bh * 64 + vrow) * 2048 + vcol;     // += kt
    const float* gM = mkb + (lane & 7) * 4;                          // += kt
    int wof = wave * 512;             // wave-uniform LDS stage offset

    // loop-invariant swizzled frag-read offsets
    int a0 = ((quad    ) ^ (l15 & 7)) * 8;    // K chunks 0..7  -> d = quad*8
    int a1 = ((4 + quad) ^ (l15 & 7)) * 8;    //                -> d = 32+quad*8
    // V b64 offsets (u16 units): chunk c stored at c ^ (d&3) ^ ((d>>2)&3);
    // d&3 == l15&3, (d>>2)&3 == (l15>>2)&3 (dt-invariant).
    int vsw = (l15 & 3) ^ ((l15 >> 2) & 3);
    int o1 = (((quad >> 1)    ) ^ vsw) * 8 + (quad & 1) * 4;
    int o2 = (((quad >> 1) + 2) ^ vsw) * 8 + (quad & 1) * 4;

    // one KVBLK=32 tile body; barrier + counted vmcnt(3) at TOP.
    auto TILE = [&](int kt, const u16* Kb, const u16* Vb, const float* Mb,
                    u16* Kn, u16* Vn, float* Mn) {
        asm volatile("s_waitcnt vmcnt(3)" ::: "memory");
        __builtin_amdgcn_s_barrier();
        __builtin_amdgcn_sched_barrier(0);
        int nkt = kt + 64; if (nkt > N_ - 32) nkt = N_ - 32;   // clamp (dead restage)
        async16(gK + (size_t)nkt * 64, Kn);
        async16(gV + nkt,              Vn);
        async16p(gM + nkt,             Mn);
        float4 mkv0 = *(const float4*)(Mb + quad * 4);
        float4 mkv1 = *(const float4*)(Mb + 16 + quad * 4);
        // S^T (key x q): C seeded with nmq*mk (mask add for free); p = exp2(S)
        float p[2][2][4];   // [s][t][r]: P[key = t*16 + quad*4 + r][q = s*16+l15]
#pragma unroll
        for (int t = 0; t < 2; t++) {
            bf16x8 kf0 = *(const bf16x8*)(Kb + (t * 16 + l15) * 64 + a0);
            bf16x8 kf1 = *(const bf16x8*)(Kb + (t * 16 + l15) * 64 + a1);
            float4 mk = t ? mkv1 : mkv0;
#pragma unroll
            for (int s = 0; s < 2; s++) {
                floatx4 sa;
                sa[0] = nmq[s] * mk.x;
                sa[1] = nmq[s] * mk.y;
                sa[2] = nmq[s] * mk.z;
                sa[3] = nmq[s] * mk.w;
                __builtin_amdgcn_s_setprio(1);
                sa = __builtin_amdgcn_mfma_f32_16x16x32_bf16(kf0, qf[s][0], sa, 0, 0, 0);
                sa = __builtin_amdgcn_mfma_f32_16x16x32_bf16(kf1, qf[s][1], sa, 0, 0, 0);
                __builtin_amdgcn_s_setprio(0);
                p[s][t][0] = fexp2(sa[0]);
                p[s][t][1] = fexp2(sa[1]);
                p[s][t][2] = fexp2(sa[2]);
                p[s][t][3] = fexp2(sa[3]);
            }
        }
        // pack P into A-fragments in-register (kappa order: j = t*4+r)
        bf16x8 pf[2];
#pragma unroll
        for (int s = 0; s < 2; s++) {
            uint4 u;
            u.x = pkraw(p[s][0][0], p[s][0][1]);
            u.y = pkraw(p[s][0][2], p[s][0][3]);
            u.z = pkraw(p[s][1][0], p[s][1][1]);
            u.w = pkraw(p[s][1][2], p[s][1][3]);
            __builtin_memcpy(&pf[s], &u, 16);
        }
        // denominator via ones-MFMA (permutation-invariant)
        __builtin_amdgcn_s_setprio(1);
        accl[0] = __builtin_amdgcn_mfma_f32_16x16x32_bf16(pf[0], onef, accl[0], 0, 0, 0);
        accl[1] = __builtin_amdgcn_mfma_f32_16x16x32_bf16(pf[1], onef, accl[1], 0, 0, 0);
        __builtin_amdgcn_s_setprio(0);
        // PV: vf assembled from two b64s in kappa key order
#pragma unroll
        for (int dt = 0; dt < 4; dt++) {
            const u16* vr = Vb + (dt * 16 + l15) * 32;
            uint2 v1 = *(const uint2*)(vr + o1);
            uint2 v2 = *(const uint2*)(vr + o2);
            uint4 vv; vv.x = v1.x; vv.y = v1.y; vv.z = v2.x; vv.w = v2.y;
            bf16x8 vf; __builtin_memcpy(&vf, &vv, 16);
            __builtin_amdgcn_s_setprio(1);
            acc[0][dt] = __builtin_amdgcn_mfma_f32_16x16x32_bf16(pf[0], vf, acc[0][dt], 0, 0, 0);
            acc[1][dt] = __builtin_amdgcn_mfma_f32_16x16x32_bf16(pf[1], vf, acc[1][dt], 0, 0, 0);
            __builtin_amdgcn_s_setprio(0);
        }
    };

    // prologue: drain qf/nmq loads so the vmcnt FIFO is clean, then stage
    // tiles 0,1 (3 ops each) and full-drain once.
    asm volatile("s_waitcnt vmcnt(0)" ::: "memory");
    async16(gK,            Ks[0] + wof);
    async16(gV,            Vs[0] + wof);
    async16p(gM,           Msr[0]);
    async16(gK + 32 * 64,  Ks[1] + wof);
    async16(gV + 32,       Vs[1] + wof);
    async16p(gM + 32,      Msr[1]);
    __syncthreads();

    // 64 tiles: 21 x 3 (ring-3, static buffers) + 1 tail
    for (int m = 0; m < 21; ++m) {
        int kt = m * 96;
        TILE(kt,      Ks[0], Vs[0], Msr[0], Ks[2] + wof, Vs[2] + wof, Msr[2]);
        TILE(kt + 32, Ks[1], Vs[1], Msr[1], Ks[0] + wof, Vs[0] + wof, Msr[0]);
        TILE(kt + 64, Ks[2], Vs[2], Msr[2], Ks[1] + wof, Vs[1] + wof, Msr[1]);
    }
    TILE(2016, Ks[0], Vs[0], Msr[0], Ks[2] + wof, Vs[2] + wof, Msr[2]);  // tile 63

    // epilogue: accl[s][r] = l(q = s*16+quad*4+r) — per-lane, no shuffles.
    // acc C-layout: col=l15=d, row=quad*4+r=q (same row-map as accl).
#pragma unroll
    for (int s = 0; s < 2; s++) {
#pragma unroll
        for (int r = 0; r < 4; r++) {
            float ir = 1.0f / accl[s][r];
            int qrow = q0 + s * 16 + quad * 4 + r;
            float* orow = out + ((size_t)(b * N_ + qrow)) * C_ + h * 64;
#pragma unroll
            for (int dt = 0; dt < 4; dt++)
                orow[dt * 16 + l15] = acc[s][dt][r] * ir;
        }
    }
}

// ---------------------------------------------------------------------------
extern "C" void kernel_launch(void* const* d_in, const int* in_sizes, int n_in,
                              void* d_out, int out_size, void* d_ws, size_t ws_size,
                              hipStream_t stream) {
    const float* inp  = (const float*)d_in[0];   // inputs  [B,N,C] fp32
    const float* mask = (const float*)d_in[1];   // mask    [B,N]   fp32
    const float* W    = (const float*)d_in[2];   // W_qkv   [C,3C]  fp32
    float* out = (float*)d_out;                  // [B,N,C] fp32

    char* ws = (char*)d_ws;
    u16* x  = (u16*)ws;                              // 16 MB  x=in+PE bf16
    u16* Wt = (u16*)(ws + 16777216);                 // 6 MB   W^T bf16
    u16* q  = (u16*)(ws + 23068672);                 // [B,H,N,64] bf16 (pre-scaled)
    u16* k  = q + 8388608;
    u16* vt = k + 8388608;                           // [B,H,64,N] bf16 (v transposed)

    pe_add_kernel<<<16384, 256, 0, stream>>>(inp, x);
    wt_kernel<<<dim3(96, 32), 256, 0, stream>>>(W, Wt);
    qkv_gemm_kernel<<<dim3(64, 24), 256, 0, stream>>>(x, Wt, q, k, vt);
    attn_kernel<<<1024, 256, 0, stream>>>(q, k, vt, mask, out);
}